// Round 3
// baseline (352.410 us; speedup 1.0000x reference)
//
#include <hip/hip_runtime.h>
#include <hip/hip_bf16.h>

#define B_ 128
#define T_ 512
#define H_ 128
#define V_ 64
#define G4_ 512  // 4*H

typedef _Float16 h2_t __attribute__((ext_vector_type(2)));
typedef _Float16 h8_t __attribute__((ext_vector_type(8)));
struct h8s { h2_t p[4]; };

__device__ __forceinline__ float dot2f(h2_t a, h2_t b, float c) {
#if __has_builtin(__builtin_amdgcn_fdot2)
  return __builtin_amdgcn_fdot2(a, b, c, false);
#else
  return fmaf((float)a[1], (float)b[1], fmaf((float)a[0], (float)b[0], c));
#endif
}

__device__ __forceinline__ float ex2(float x) {
#if __has_builtin(__builtin_amdgcn_exp2f)
  return __builtin_amdgcn_exp2f(x);
#else
  return exp2f(x);
#endif
}

__device__ __forceinline__ float rcpf_(float x) {
#if __has_builtin(__builtin_amdgcn_rcpf)
  return __builtin_amdgcn_rcpf(x);
#else
  return 1.0f / x;
#endif
}

// DPP quad-perm controls
#define QP_XOR1 0xB1  // [1,0,3,2]
#define QP_XOR2 0x4E  // [2,3,0,1]
#define QP_BC0 0x00
#define QP_BC1 0x55
#define QP_BC2 0xAA
#define QP_BC3 0xFF

template <int CTRL>
__device__ __forceinline__ float qperm(float v) {
#if __has_builtin(__builtin_amdgcn_update_dpp)
  return __builtin_bit_cast(
      float, __builtin_amdgcn_update_dpp(0, __builtin_bit_cast(int, v), CTRL,
                                         0xf, 0xf, true));
#else
  int lane = (int)(threadIdx.x & 3);
  int src;
  if constexpr (CTRL == QP_XOR1) src = lane ^ 1;
  else if constexpr (CTRL == QP_XOR2) src = lane ^ 2;
  else src = CTRL & 3;
  return __shfl(v, ((int)threadIdx.x & ~3) + src, 64);
#endif
}

// ---------------------------------------------------------------------------
// K1: P[dir][v][k*4+g] = dot(emb[v,:], w_ih[dir][g*128+k,:]) + biases
// Layout [v][k*4+g] so k_scan's quad-strided read is 64 consecutive floats
// per wave (conflict-free).
// ---------------------------------------------------------------------------
__global__ __launch_bounds__(512) void k_tables(
    const float* __restrict__ emb,
    const float* __restrict__ w_ih_f, const float* __restrict__ b_ih_f,
    const float* __restrict__ b_hh_f,
    const float* __restrict__ w_ih_b, const float* __restrict__ b_ih_b,
    const float* __restrict__ b_hh_b,
    float* __restrict__ Ptab) {
  const int dir = blockIdx.x >> 6;
  const int v = blockIdx.x & 63;
  const int j = threadIdx.x;  // row = g*128 + k
  const float* w_ih = dir ? w_ih_b : w_ih_f;
  const float* bi = dir ? b_ih_b : b_ih_f;
  const float* bh = dir ? b_hh_b : b_hh_f;
  const float4* e4 = (const float4*)(emb + v * H_);
  const float4* w4 = (const float4*)(w_ih + j * H_);
  float a0 = 0.f, a1 = 0.f, a2 = 0.f, a3 = 0.f;
#pragma unroll
  for (int q = 0; q < H_ / 4; ++q) {
    float4 e = e4[q];
    float4 w = w4[q];
    a0 = fmaf(e.x, w.x, a0);
    a1 = fmaf(e.y, w.y, a1);
    a2 = fmaf(e.z, w.z, a2);
    a3 = fmaf(e.w, w.w, a3);
  }
  const int g = j >> 7, k = j & 127;
  Ptab[dir * (V_ * G4_) + v * G4_ + (k << 2) + g] =
      (a0 + a1) + (a2 + a3) + bi[j] + bh[j];
}

// ---------------------------------------------------------------------------
// K2: persistent per-(batch,dir) LSTM scan. grid = 256, block = 512.
// Lane mapping: wave w, lane l -> k = w*16 + (l>>2), gate g = l&3.
// No global stores in the step loop: h history buffered in LDS (64 steps),
// flushed with coalesced 16B stores. P value + x index prefetched 1 step
// ahead into rolling registers.
// ---------------------------------------------------------------------------
__global__ __launch_bounds__(512, 1) void k_scan(
    const int* __restrict__ x,
    const float* __restrict__ w_hh_f,
    const float* __restrict__ w_hh_b,
    const float* __restrict__ Ptab,
    _Float16* __restrict__ hs) {
  __shared__ __align__(16) float P[V_ * G4_];          // 128 KB
  __shared__ int xoff[T_];                             // 2 KB
  __shared__ __align__(16) _Float16 hb[2][H_];         // 512 B
  __shared__ __align__(16) _Float16 hist[64][H_];      // 16 KB

  const int tid = threadIdx.x;
  const int b = blockIdx.x >> 1;
  const int dir = blockIdx.x & 1;
  const int l = tid & 63;
  const int w = tid >> 6;
  const int g = l & 3;
  const int k = (w << 4) + (l >> 2);
  const int k4g = (k << 2) + g;

  // stage P table, coalesced float4
  {
    const float4* src = (const float4*)(Ptab + dir * (V_ * G4_));
    float4* dst = (float4*)P;
#pragma unroll
    for (int i = 0; i < (V_ * G4_ / 4) / 512; ++i)
      dst[tid + i * 512] = src[tid + i * 512];
  }
  xoff[tid] = x[(b << 9) + tid] << 9;
  if (tid < H_) hb[0][tid] = (_Float16)0.f;

  // load weight quarters: rows g*128+k, elements [g*32, g*32+32), fp16 pairs
  const float* W = dir ? w_hh_b : w_hh_f;
  h2_t wr[4][16];
#pragma unroll
  for (int j = 0; j < 4; ++j) {
    const float2* wp = (const float2*)(W + (j * H_ + k) * H_ + g * 32);
#pragma unroll
    for (int e = 0; e < 16; ++e) {
      float2 ww = wp[e];
      wr[j][e] = h2_t{(_Float16)ww.x, (_Float16)ww.y};
    }
  }

  // per-lane nonlinearity constants: sigm for g in {0,1,3}, tanh for g==2
  const float nm = (g == 2) ? -2.8853900817779268f : -1.4426950408889634f;
  const float sa = (g == 2) ? 2.f : 1.f;
  const float sb = (g == 2) ? -1.f : 0.f;

  float c0 = 0.f;  // c[k], replicated across the quad

  __syncthreads();

  // preload step-0 P value
  float pv = P[xoff[dir ? (T_ - 1) : 0] + k4g];

  int cur = 0;
  for (int s = 0; s < T_; ++s) {
    const int t = dir ? (T_ - 1 - s) : s;
    // h quarter g: 4x ds_read_b128 (broadcast within 16-lane groups)
    const h8_t* hq8 = (const h8_t*)(&hb[cur][g << 5]);
    h8s q0 = __builtin_bit_cast(h8s, hq8[0]);
    h8s q1 = __builtin_bit_cast(h8s, hq8[1]);
    h8s q2 = __builtin_bit_cast(h8s, hq8[2]);
    h8s q3 = __builtin_bit_cast(h8s, hq8[3]);

    // prefetch next step's P value (consumed next iteration)
    const int sn = (s < T_ - 1) ? s + 1 : s;
    const int tn = dir ? (T_ - 1 - sn) : sn;
    const float pvn = P[xoff[tn] + k4g];

    float a0 = 0.f, a1 = 0.f, a2 = 0.f, a3 = 0.f;
#pragma unroll
    for (int e = 0; e < 4; ++e) {
      a0 = dot2f(q0.p[e], wr[0][e], a0);
      a1 = dot2f(q0.p[e], wr[1][e], a1);
      a2 = dot2f(q0.p[e], wr[2][e], a2);
      a3 = dot2f(q0.p[e], wr[3][e], a3);
    }
#pragma unroll
    for (int e = 0; e < 4; ++e) {
      a0 = dot2f(q1.p[e], wr[0][4 + e], a0);
      a1 = dot2f(q1.p[e], wr[1][4 + e], a1);
      a2 = dot2f(q1.p[e], wr[2][4 + e], a2);
      a3 = dot2f(q1.p[e], wr[3][4 + e], a3);
    }
#pragma unroll
    for (int e = 0; e < 4; ++e) {
      a0 = dot2f(q2.p[e], wr[0][8 + e], a0);
      a1 = dot2f(q2.p[e], wr[1][8 + e], a1);
      a2 = dot2f(q2.p[e], wr[2][8 + e], a2);
      a3 = dot2f(q2.p[e], wr[3][8 + e], a3);
    }
#pragma unroll
    for (int e = 0; e < 4; ++e) {
      a0 = dot2f(q3.p[e], wr[0][12 + e], a0);
      a1 = dot2f(q3.p[e], wr[1][12 + e], a1);
      a2 = dot2f(q3.p[e], wr[2][12 + e], a2);
      a3 = dot2f(q3.p[e], wr[3][12 + e], a3);
    }

    // quad transpose-reduce: lane ends with full dot for its row g
    float s0 = a0 + qperm<QP_XOR1>(a0);
    float s1 = a1 + qperm<QP_XOR1>(a1);
    float s2 = a2 + qperm<QP_XOR1>(a2);
    float s3 = a3 + qperm<QP_XOR1>(a3);
    float A = (g & 1) ? s1 : s0;
    float Bv = (g & 1) ? s3 : s2;
    float A2 = A + qperm<QP_XOR2>(A);
    float B2 = Bv + qperm<QP_XOR2>(Bv);
    float gv = ((g & 2) ? B2 : A2) + pv;

    // nonlinearity (uniform code, per-lane constants)
    float e0 = ex2(nm * gv);
    float r0 = rcpf_(1.f + e0);
    float y = fmaf(sa, r0, sb);

    // broadcast all 4 gates within the quad
    float yi = qperm<QP_BC0>(y);
    float yf = qperm<QP_BC1>(y);
    float yg = qperm<QP_BC2>(y);
    float yo = qperm<QP_BC3>(y);

    c0 = fmaf(yf, c0, yi * yg);
    float ec = ex2(-2.8853900817779268f * c0);
    float rc = rcpf_(1.f + ec);
    float tc = fmaf(2.f, rc, -1.f);
    float ht = yo * tc;

    if (g == 0) {
      _Float16 hh = (_Float16)ht;
      hb[cur ^ 1][k] = hh;
      hist[t & 63][k] = hh;
    }

    if ((s & 63) == 63) {
      // all 64 rows of hist complete -> bulk flush (coalesced 16B stores)
      __syncthreads();
      const int base = t & ~63;
#pragma unroll
      for (int it = 0; it < 2; ++it) {
        int idx = it * 512 + tid;
        int tl = idx >> 4, q = idx & 15;
        h8_t v8 = *(const h8_t*)(&hist[tl][q << 3]);
        *(h8_t*)(hs + (((size_t)((b << 9) + base + tl)) << 8) + (dir << 7) +
                 (q << 3)) = v8;
      }
    }
    __syncthreads();
    pv = pvn;
    cur ^= 1;
  }
}

// ---------------------------------------------------------------------------
// K3: out[row, v] = dot(hs[row, 0:256], fc_w[v, 0:256]) + fc_b[v]
// ---------------------------------------------------------------------------
__global__ __launch_bounds__(256) void k_fc(
    const _Float16* __restrict__ hs,
    const float* __restrict__ fc_w,
    const float* __restrict__ fc_b,
    float* __restrict__ out) {
  __shared__ __align__(16) _Float16 Wl[V_ * 2 * H_];  // 32 KB
  __shared__ float bl[V_];
  const int tid = threadIdx.x;
  for (int i = tid; i < V_ * 2 * H_; i += 256) Wl[i] = (_Float16)fc_w[i];
  if (tid < V_) bl[tid] = fc_b[tid];
  __syncthreads();

  const size_t row = (size_t)blockIdx.x * 256 + tid;
  const h8_t* h8 = (const h8_t*)(hs + (row << 8));
  float acc[V_];
#pragma unroll
  for (int v = 0; v < V_; ++v) acc[v] = 0.f;

  for (int ch = 0; ch < 8; ++ch) {  // 8 chunks of 32 h-elements
    h8s hv0 = __builtin_bit_cast(h8s, h8[ch * 4 + 0]);
    h8s hv1 = __builtin_bit_cast(h8s, h8[ch * 4 + 1]);
    h8s hv2 = __builtin_bit_cast(h8s, h8[ch * 4 + 2]);
    h8s hv3 = __builtin_bit_cast(h8s, h8[ch * 4 + 3]);
#pragma unroll
    for (int v = 0; v < V_; ++v) {
      const h8_t* w8 = (const h8_t*)(Wl + v * 256 + ch * 32);
      float a = acc[v];
      h8s wv = __builtin_bit_cast(h8s, w8[0]);
      a = dot2f(hv0.p[0], wv.p[0], a);
      a = dot2f(hv0.p[1], wv.p[1], a);
      a = dot2f(hv0.p[2], wv.p[2], a);
      a = dot2f(hv0.p[3], wv.p[3], a);
      wv = __builtin_bit_cast(h8s, w8[1]);
      a = dot2f(hv1.p[0], wv.p[0], a);
      a = dot2f(hv1.p[1], wv.p[1], a);
      a = dot2f(hv1.p[2], wv.p[2], a);
      a = dot2f(hv1.p[3], wv.p[3], a);
      wv = __builtin_bit_cast(h8s, w8[2]);
      a = dot2f(hv2.p[0], wv.p[0], a);
      a = dot2f(hv2.p[1], wv.p[1], a);
      a = dot2f(hv2.p[2], wv.p[2], a);
      a = dot2f(hv2.p[3], wv.p[3], a);
      wv = __builtin_bit_cast(h8s, w8[3]);
      a = dot2f(hv3.p[0], wv.p[0], a);
      a = dot2f(hv3.p[1], wv.p[1], a);
      a = dot2f(hv3.p[2], wv.p[2], a);
      a = dot2f(hv3.p[3], wv.p[3], a);
      acc[v] = a;
    }
  }
  float* orow = out + (row << 6);
#pragma unroll
  for (int v = 0; v < V_; v += 4) {
    float4 o = make_float4(acc[v] + bl[v], acc[v + 1] + bl[v + 1],
                           acc[v + 2] + bl[v + 2], acc[v + 3] + bl[v + 3]);
    *(float4*)(orow + v) = o;
  }
}

extern "C" void kernel_launch(void* const* d_in, const int* in_sizes, int n_in,
                              void* d_out, int out_size, void* d_ws, size_t ws_size,
                              hipStream_t stream) {
  const int* x = (const int*)d_in[0];
  const float* emb = (const float*)d_in[1];
  const float* w_ih_f = (const float*)d_in[2];
  const float* w_hh_f = (const float*)d_in[3];
  const float* b_ih_f = (const float*)d_in[4];
  const float* b_hh_f = (const float*)d_in[5];
  const float* w_ih_b = (const float*)d_in[6];
  const float* w_hh_b = (const float*)d_in[7];
  const float* b_ih_b = (const float*)d_in[8];
  const float* b_hh_b = (const float*)d_in[9];
  const float* fc_w = (const float*)d_in[10];
  const float* fc_b = (const float*)d_in[11];
  float* out = (float*)d_out;

  // workspace layout: [P tables: 2*64*512 fp32 = 256 KB][hs: B*T*256 fp16 = 32 MB]
  float* Ptab = (float*)d_ws;
  _Float16* hs = (_Float16*)((char*)d_ws + (size_t)2 * V_ * G4_ * sizeof(float));

  k_tables<<<2 * V_, G4_, 0, stream>>>(emb, w_ih_f, b_ih_f, b_hh_f, w_ih_b,
                                       b_ih_b, b_hh_b, Ptab);
  k_scan<<<B_ * 2, G4_, 0, stream>>>(x, w_hh_f, w_hh_b, Ptab, hs);
  k_fc<<<B_ * T_ / 256, 256, 0, stream>>>(hs, fc_w, fc_b, out);
}